// Round 9
// baseline (75.123 us; speedup 1.0000x reference)
//
#include <hip/hip_runtime.h>
#include <hip/hip_bf16.h>
#include <stdint.h>

#define BATCH 8
#define CCH 96
#define NH 3
#define HD 32
#define HGT 56
#define WID 56
#define HW 3136
#define WIN 7
#define KK 49
#define PADR 3
#define NIMG 24   // BATCH*NH
#define C2 64     // 2*HD

typedef const float* fp32p;
typedef __attribute__((ext_vector_type(8))) short bf16x8;
typedef __attribute__((ext_vector_type(16))) float f32x16;
typedef __attribute__((ext_vector_type(2))) float f32x2;
typedef unsigned short ushort_t;

__device__ __forceinline__ float bf2f_bits(unsigned u){ return __uint_as_float(u << 16); }
__device__ __forceinline__ ushort_t f2bf_bits(float f){
  __hip_bfloat16 hb = __float2bfloat16(f);
  return *(ushort_t*)&hb;
}

// ---------------------------------------------------------------------------
// prep+xt fused: blocks [0,929) weight prep, [929,1125) transpose x.
// ---------------------------------------------------------------------------
__global__ __launch_bounds__(256) void prep_xt_kernel(fp32p w_dm, fp32p b_dm,
    fp32p bias_table, fp32p w_qkv, fp32p w_proj, fp32p x,
    __hip_bfloat16* __restrict__ w3, float* __restrict__ bias3,
    ushort_t* __restrict__ wq3, ushort_t* __restrict__ wp3,
    ushort_t* __restrict__ xbf){
  __shared__ float lds[128*97];
  int bx = blockIdx.x;
  if (bx < 929){
    int t = bx * 256 + threadIdx.x;
    if (t < 200704){
      int j   = t & 7;
      int l   = (t >> 3) & 63;
      int mt  = (t >> 9) & 1;
      int cb  = (t >> 10) & 1;
      int pt  = t >> 11;            // pass*49 + tap
      int pass = pt / KK, tap = pt % KK;
      int o  = mt*32 + (l & 31);
      int ch = pass*32 + cb*16 + (l >> 5)*8 + j;
      float v = 0.f;
      if (o < KK) v = w_dm[((size_t)(o*C2 + ch))*KK + tap];
      w3[t] = __float2bfloat16(v);
    } else if (t < 200896){
      int t2 = t - 200704;
      int h = t2 >> 6;
      int o = t2 & 63;
      bias3[t2] = (o < KK) ? (b_dm[o] + bias_table[o*NH + h]) : -1e30f;
    } else if (t < 200896 + 27648){
      int i = t - 200896;
      int j = i & 7, l = (i >> 3) & 63;
      int rest = i >> 9;            // k*9 + mt
      int mt = rest % 9, k = rest / 9;
      int o = mt*32 + (l & 31);
      int c = k*16 + (l >> 5)*8 + j;
      wq3[i] = f2bf_bits(w_qkv[o*CCH + c]);
    } else if (t < 200896 + 27648 + 9216){
      int i = t - 200896 - 27648;
      int j = i & 7, l = (i >> 3) & 63;
      int rest = i >> 9;            // k*3 + mt
      int mt = rest % 3, k = rest / 3;
      int o = mt*32 + (l & 31);
      int c = k*16 + (l >> 5)*8 + j;
      wp3[i] = f2bf_bits(w_proj[o*CCH + c]);
    }
  } else {
    int px0 = (bx - 929) * 128;
    int tid = threadIdx.x;
    #pragma unroll
    for (int it = 0; it < 48; ++it){
      int s = tid + it*256;         // 12288 = 128 px * 96 c, px fastest
      int px = s & 127;
      int c  = s >> 7;
      int gpx = px0 + px;
      int b = gpx / HW, pp = gpx % HW;
      lds[px*97 + c] = x[((size_t)b*CCH + c)*HW + pp];
    }
    __syncthreads();
    #pragma unroll
    for (int it = 0; it < 6; ++it){
      int s = tid + it*256;         // 1536 = 128 px * 12 chunks
      int j  = s % 12;
      int px = s / 12;
      unsigned u[4];
      #pragma unroll
      for (int q = 0; q < 4; ++q){
        float f0 = lds[px*97 + j*8 + 2*q];
        float f1 = lds[px*97 + j*8 + 2*q + 1];
        u[q] = (unsigned)f2bf_bits(f0) | ((unsigned)f2bf_bits(f1) << 16);
      }
      uint4 w4; w4.x=u[0]; w4.y=u[1]; w4.z=u[2]; w4.w=u[3];
      *(uint4*)((char*)xbf + ((size_t)(px0+px)*96 + j*8)*2) = w4;
    }
  }
}

// ---------------------------------------------------------------------------
// qkv GEMM (R9): 3 g-waves merged per px-tile block (784 x 192 thr).
// The 3 waves load the IDENTICAL xbf B-tile -> L1 dedupe (was 3 CU misses).
// ---------------------------------------------------------------------------
__global__ __launch_bounds__(192) void qkv_kernel(const ushort_t* __restrict__ xbf,
    const ushort_t* __restrict__ wq3, fp32p b_qkv,
    ushort_t* __restrict__ qplane, ushort_t* __restrict__ kplane,
    ushort_t* __restrict__ v2){
  int pt = blockIdx.x;
  int g  = threadIdx.x >> 6;      // wave = sec: 0=q,1=k,2=v
  int l = threadIdx.x & 63, col = l & 31, hi = l >> 5;
  int px = pt*32 + col;
  int b = px / HW, pp = px % HW;

  bf16x8 B[6];
  const char* bb = (const char*)xbf + (size_t)px*192 + hi*16;
  #pragma unroll
  for (int k = 0; k < 6; ++k) B[k] = *(const bf16x8*)(bb + k*32);

  f32x16 acc[3];
  #pragma unroll
  for (int m = 0; m < 3; ++m)
    #pragma unroll
    for (int r = 0; r < 16; ++r) acc[m][r] = 0.f;

  #pragma unroll
  for (int k = 0; k < 6; ++k){
    #pragma unroll
    for (int m = 0; m < 3; ++m){
      bf16x8 A = *(const bf16x8*)((const char*)wq3 + ((size_t)((k*9 + g*3 + m)*64 + l))*16);
      acc[m] = __builtin_amdgcn_mfma_f32_32x32x16_bf16(A, B[k], acc[m], 0, 0, 0);
    }
  }
  const float scale = 0.17677669529663687f;
  ushort_t* plane = (g == 0) ? qplane : (g == 1 ? kplane : v2);
  #pragma unroll
  for (int m = 0; m < 3; ++m){    // head = m, ch = rowv
    ushort_t* dst = plane + ((size_t)((b*NH + m)*HW + pp))*32;
    #pragma unroll
    for (int q = 0; q < 4; ++q){
      int base = 8*q + 4*hi;      // rowv base; r = q*4+e -> rowv = base+e
      float v0 = acc[m][q*4+0] + b_qkv[g*96 + m*32 + base + 0];
      float v1 = acc[m][q*4+1] + b_qkv[g*96 + m*32 + base + 1];
      float v2f = acc[m][q*4+2] + b_qkv[g*96 + m*32 + base + 2];
      float v3 = acc[m][q*4+3] + b_qkv[g*96 + m*32 + base + 3];
      if (g == 0){ v0 *= scale; v1 *= scale; v2f *= scale; v3 *= scale; }
      uint2 pk;
      pk.x = (unsigned)f2bf_bits(v0) | ((unsigned)f2bf_bits(v1) << 16);
      pk.y = (unsigned)f2bf_bits(v2f) | ((unsigned)f2bf_bits(v3) << 16);
      *(uint2*)(&dst[base]) = pk;
    }
  }
}

// ---------------------------------------------------------------------------
// attn fused. R9: conv A-prefetch depth-4 (B depth-2) with memory-clobber
// scheduling fences so the allocator can't sink the loads (R2 lesson);
// V-preload pinned by asm anchor before the P barrier; P region stride
// 68->72 ushorts (144B, 16B-aligned) so PV reads P via 7x ds_read_b128
// (conflict-free: odd 16B-unit stride). XCD-clustered blocks (R8, FETCH
// 28.9->8.8MB). Waves split K: wave = (row, cbw), M64 x N64 x K16.
// LDS: [0,32KB) qk halo / exchange / V; [32KB,50KB) P (stride 72).
// ---------------------------------------------------------------------------
#define MFMA4K(Ab, Bb) \
  { _Pragma("unroll") for (int nt = 0; nt < 2; ++nt){ \
      acc[0][nt] = __builtin_amdgcn_mfma_f32_32x32x16_bf16(Ab[0], Bb[nt], acc[0][nt], 0, 0, 0); \
      acc[1][nt] = __builtin_amdgcn_mfma_f32_32x32x16_bf16(Ab[1], Bb[nt], acc[1][nt], 0, 0, 0); \
    } }

#define LOADAK(tt, Ab) \
  { const char* An_ = Abase + (size_t)(tt)*4096; \
    Ab[0] = *(const bf16x8*)(An_); \
    Ab[1] = *(const bf16x8*)(An_ + 1024); }

#define LOADBK(tt, Bb) \
  { int ky_ = (tt) / 7, kx_ = (tt) - ky_*7; \
    _Pragma("unroll") for (int nt = 0; nt < 2; ++nt){ \
      int xp_ = nt*32 + col + kx_; if (xp_ > 61) xp_ = 61; \
      int base_ = ((row + ky_)*64 + xp_)*64; \
      int sx_ = (xp_ & 3) ^ ((xp_ >> 2) & 3); \
      Bb[nt] = *(const bf16x8*)(&smem[base_ + ((((cbw << 1) | hi) ^ sx_) << 4)]); } }

#define SCHED_FENCE() asm volatile("" ::: "memory")

// exchange: chunk index within a px row = mt*8 + 2q + hi, XOR col&15 for banks
#define XWRITE(A0v, A1v) \
  { _Pragma("unroll") for (int q = 0; q < 4; ++q){ \
      float4 v4; \
      v4.x=A0v[4*q+0]; v4.y=A0v[4*q+1]; v4.z=A0v[4*q+2]; v4.w=A0v[4*q+3]; \
      *(float4*)((char*)xch + slot_o*256 + (((2*q+hi) ^ xsw)<<4)) = v4; \
      v4.x=A1v[4*q+0]; v4.y=A1v[4*q+1]; v4.z=A1v[4*q+2]; v4.w=A1v[4*q+3]; \
      *(float4*)((char*)xch + slot_o*256 + (((8+2*q+hi) ^ xsw)<<4)) = v4; } }

#define XREAD(A0v, A1v) \
  { _Pragma("unroll") for (int q = 0; q < 4; ++q){ \
      float4 v4 = *(const float4*)((char*)xch + slot_s*256 + (((2*q+hi) ^ xsw)<<4)); \
      A0v[4*q+0]+=v4.x; A0v[4*q+1]+=v4.y; A0v[4*q+2]+=v4.z; A0v[4*q+3]+=v4.w; \
      v4 = *(const float4*)((char*)xch + slot_s*256 + (((8+2*q+hi) ^ xsw)<<4)); \
      A1v[4*q+0]+=v4.x; A1v[4*q+1]+=v4.y; A1v[4*q+2]+=v4.z; A1v[4*q+3]+=v4.w; } }

__global__ __launch_bounds__(256, 3) void attn_kernel(
    const ushort_t* __restrict__ qplane, const ushort_t* __restrict__ kplane,
    const __hip_bfloat16* __restrict__ w3, const float* __restrict__ bias3,
    const ushort_t* __restrict__ v2, ushort_t* __restrict__ tmp2){
  __shared__ char smem[51200];

  int d = blockIdx.x;
  int bid = (d & 7)*84 + (d >> 3);  // XCD-cluster: 84 consecutive blocks/XCD
  int n  = bid / 28;
  int y0 = (bid % 28) * 2;
  int b = n / NH, head = n % NH;
  int tid = threadIdx.x;
  int l = tid & 63, w = tid >> 6, hi = l >> 5, col = l & 31;
  int row = w >> 1;               // output row within the pair
  int cbw = w & 1;                // K-half this wave accumulates

  f32x16 acc[2][2];               // [mt][nt] partial sums for K-half cbw
  #pragma unroll
  for (int r = 0; r < 16; ++r){
    int rowv = (r & 3) + 8*(r >> 2) + 4*hi;
    float b0 = (cbw == 0) ? bias3[head*64 + rowv] : 0.f;
    float b1 = (cbw == 0) ? bias3[head*64 + 32 + rowv] : 0.f;
    #pragma unroll
    for (int nt = 0; nt < 2; ++nt){ acc[0][nt][r] = b0; acc[1][nt][r] = b1; }
  }

  for (int pass = 0; pass < 2; ++pass){
    if (pass) __syncthreads();
    const char* src = (const char*)(pass ? kplane : qplane) + (size_t)n * HW * 64;
    #pragma unroll
    for (int it = 0; it < 8; ++it){
      int s = tid + it*256;       // 2048 16B chunks: 8 rows x 64 xp x 4 c
      int c   = s & 3;
      int xp  = (s >> 2) & 63;
      int rw  = s >> 8;
      int gy = y0 - 3 + rw;
      int gx = xp - 3;
      uint4 val = {0,0,0,0};
      if ((unsigned)gy < HGT && (unsigned)gx < WID)
        val = *(const uint4*)(src + (size_t)(gy*WID + gx)*64 + c*16);
      int sw = (c ^ (xp & 3) ^ ((xp >> 2) & 3)) << 4;
      *(uint4*)(&smem[(rw*64 + xp)*64 + sw]) = val;
    }
    __syncthreads();

    const char* Abase = (const char*)w3 + (size_t)pass*KK*4096 + cbw*2048 + l*16;
    // A depth-4, B depth-2; fences pin load issue points (R2: allocator
    // otherwise sinks the prefetch and de-pipelines).
    bf16x8 A0[2], A1[2], A2[2], A3[2], B0[2], B1[2];
    LOADAK(0, A0); LOADAK(1, A1); LOADAK(2, A2); LOADAK(3, A3);
    LOADBK(0, B0); LOADBK(1, B1);
    SCHED_FENCE();
    for (int t = 0; t < 48; t += 4){
      int ta0 = (t+4 < KK) ? t+4 : 48;
      int ta1 = (t+5 < KK) ? t+5 : 48;
      int ta2 = (t+6 < KK) ? t+6 : 48;
      int ta3 = (t+7 < KK) ? t+7 : 48;
      int tb2 = (t+2 < KK) ? t+2 : 48;
      int tb3 = (t+3 < KK) ? t+3 : 48;
      int tb4 = (t+4 < KK) ? t+4 : 48;
      int tb5 = (t+5 < KK) ? t+5 : 48;
      MFMA4K(A0, B0); LOADBK(tb2, B0); LOADAK(ta0, A0);
      MFMA4K(A1, B1); LOADBK(tb3, B1); LOADAK(ta1, A1);
      SCHED_FENCE();
      MFMA4K(A2, B0); LOADBK(tb4, B0); LOADAK(ta2, A2);
      MFMA4K(A3, B1); LOADBK(tb5, B1); LOADAK(ta3, A3);
      SCHED_FENCE();
    }
    MFMA4K(A0, B0);               // tap 48
  }

  // cross-wave cb-partial exchange via dead qk-halo LDS. Wave (row,cbw)
  // writes px-half (1-cbw), reads+merges its own half cbw.
  __syncthreads();                // all waves done reading qk halo
  float* xch = (float*)smem;
  int xsw = col & 15;
  {
    int slot_o = row*64 + (1-cbw)*32 + col;
    if (cbw == 0){ XWRITE(acc[0][1], acc[1][1]); }
    else         { XWRITE(acc[0][0], acc[1][0]); }
  }
  __syncthreads();
  f32x16 a0, a1;                  // merged logits for owned px-half
  {
    int slot_s = row*64 + cbw*32 + col;
    if (cbw == 0){ XREAD(acc[0][0], acc[1][0]); a0 = acc[0][0]; a1 = acc[1][0]; }
    else         { XREAD(acc[0][1], acc[1][1]); a0 = acc[0][1]; a1 = acc[1][1]; }
  }

  // V preload (global->reg); anchored below so issue happens HERE, with the
  // latency hiding under softmax + P-stores (compiler sank it in R3/R4).
  const char* vb = (const char*)v2 + (size_t)n * HW * 64;
  uint4 vreg[8];
  #pragma unroll
  for (int it = 0; it < 8; ++it){
    int s = tid + it*256;         // 2048
    int xp  = s & 63;
    int c   = (s >> 6) & 3;
    int rw  = s >> 8;
    int gy = y0 - 3 + rw;
    int gx = xp - 3;
    uint4 val = {0,0,0,0};
    if ((unsigned)gy < HGT && (unsigned)gx < WID)
      val = *(const uint4*)(vb + (size_t)(gy*WID + gx)*64 + c*16);
    vreg[it] = val;
  }

  // softmax over 64 padded o; P -> LDS [128 px][stride 72] bf16 (b64 stores)
  ushort_t* Pp = (ushort_t*)&smem[32768];
  {
    float m = -1e30f;
    #pragma unroll
    for (int r = 0; r < 16; ++r){ m = fmaxf(m, a0[r]); m = fmaxf(m, a1[r]); }
    m = fmaxf(m, __shfl_xor(m, 32));
    float s = 0.f;
    #pragma unroll
    for (int r = 0; r < 16; ++r){
      a0[r] = __expf(a0[r] - m); s += a0[r];
      a1[r] = __expf(a1[r] - m); s += a1[r];
    }
    s += __shfl_xor(s, 32);
    float inv = 1.f / s;
    int pixslot = row*64 + cbw*32 + col;
    ushort_t* Pr = Pp + pixslot*72;
    #pragma unroll
    for (int q = 0; q < 4; ++q){
      int base = 8*q + 4*hi;      // rowv base; r = q*4+e -> rowv = base+e
      uint2 pk0;
      pk0.x = (unsigned)f2bf_bits(a0[q*4+0]*inv) | ((unsigned)f2bf_bits(a0[q*4+1]*inv) << 16);
      pk0.y = (unsigned)f2bf_bits(a0[q*4+2]*inv) | ((unsigned)f2bf_bits(a0[q*4+3]*inv) << 16);
      *(uint2*)(&Pr[base]) = pk0;
      uint2 pk1;                  // o = 32+base..+3; slots >=49 never read by PV
      pk1.x = (unsigned)f2bf_bits(a1[q*4+0]*inv) | ((unsigned)f2bf_bits(a1[q*4+1]*inv) << 16);
      pk1.y = (unsigned)f2bf_bits(a1[q*4+2]*inv) | ((unsigned)f2bf_bits(a1[q*4+3]*inv) << 16);
      *(uint2*)(&Pr[32 + base]) = pk1;
    }
  }
  // anchor: forces the V loads to have been ISSUED before this point
  asm volatile("" :: "v"(vreg[0].x), "v"(vreg[1].x), "v"(vreg[2].x),
                     "v"(vreg[3].x), "v"(vreg[4].x), "v"(vreg[5].x),
                     "v"(vreg[6].x), "v"(vreg[7].x));
  __syncthreads();                // exchange reads + P writes all done

  // V restage from regs, transposed: [c4][row8][xp64][16B] -> conflict-free PV
  #pragma unroll
  for (int it = 0; it < 8; ++it){
    int s = tid + it*256;         // 2048
    int xp  = s & 63;
    int c   = (s >> 6) & 3;
    int rw  = s >> 8;
    *(uint4*)(&smem[((c*8 + rw)*64 + xp)*16]) = vreg[it];
  }
  __syncthreads();

  // PV: 2 threads per px (128 slots x 2 ch-halves), 16 ch each.
  // P row read via 7x ds_read_b128 into regs (stride 144B: conflict-free).
  int ch2 = tid >> 7;             // channel half
  int slot = tid & 127;
  int pr = slot >> 6, pxx = slot & 63;
  if (pxx < WID){
    unsigned pw_[28];             // 56 ushorts; taps 0..48 used
    #pragma unroll
    for (int i = 0; i < 7; ++i){
      uint4 v4 = *(const uint4*)(&Pp[slot*72 + i*8]);
      pw_[i*4+0] = v4.x; pw_[i*4+1] = v4.y; pw_[i*4+2] = v4.z; pw_[i*4+3] = v4.w;
    }
    f32x2 out2[8];                // [ci*4+q] = channel pair (2q, 2q+1) of ci
    #pragma unroll
    for (int i = 0; i < 8; ++i){ out2[i].x = 0.f; out2[i].y = 0.f; }
    #pragma unroll
    for (int ky = 0; ky < WIN; ++ky){
      #pragma unroll
      for (int kx = 0; kx < WIN; ++kx){
        const int o = ky*7 + kx;
        unsigned wv = pw_[o >> 1];
        float pw = (o & 1) ? __uint_as_float(wv & 0xffff0000u)
                           : __uint_as_float(wv << 16);
        f32x2 pw2; pw2.x = pw; pw2.y = pw;
        int vrow = pr + ky, xp = pxx + kx;
        #pragma unroll
        for (int ci = 0; ci < 2; ++ci){
          int cc = ch2*2 + ci;
          uint4 vv = *(const uint4*)(&smem[((cc*8 + vrow)*64 + xp)*16]);
          unsigned ua[4] = {vv.x, vv.y, vv.z, vv.w};
          #pragma unroll
          for (int q = 0; q < 4; ++q){
            f32x2 v2f;
            v2f.x = __uint_as_float(ua[q] << 16);
            v2f.y = __uint_as_float(ua[q] & 0xffff0000u);
            out2[ci*4 + q] += pw2 * v2f;
          }
        }
      }
    }
    int pp = (y0 + pr)*WID + pxx;
    ushort_t* dst = tmp2 + ((size_t)(b*HW + pp))*96 + head*32 + ch2*16;
    #pragma unroll
    for (int j2 = 0; j2 < 2; ++j2){
      unsigned u[4];
      #pragma unroll
      for (int q = 0; q < 4; ++q){
        u[q] = (unsigned)f2bf_bits(out2[j2*4 + q].x) | ((unsigned)f2bf_bits(out2[j2*4 + q].y) << 16);
      }
      uint4 w4; w4.x=u[0]; w4.y=u[1]; w4.z=u[2]; w4.w=u[3];
      *(uint4*)(&dst[j2*8]) = w4;
    }
  }
}

// ---------------------------------------------------------------------------
// proj GEMM: wave = M96 x N32; grid = 784 px-tiles (R4 form — proven).
// ---------------------------------------------------------------------------
__global__ __launch_bounds__(64) void proj_kernel(const ushort_t* __restrict__ tmp2,
    const ushort_t* __restrict__ wp3, fp32p b_proj, float* __restrict__ outp){
  int pt = blockIdx.x;
  int l = threadIdx.x & 63, col = l & 31, hi = l >> 5;
  int px = pt*32 + col;
  int b = px / HW, pp = px % HW;

  bf16x8 B[6];
  const char* bb = (const char*)tmp2 + (size_t)px*192 + hi*16;
  #pragma unroll
  for (int k = 0; k < 6; ++k) B[k] = *(const bf16x8*)(bb + k*32);

  f32x16 acc[3];
  #pragma unroll
  for (int m = 0; m < 3; ++m)
    #pragma unroll
    for (int r = 0; r < 16; ++r) acc[m][r] = 0.f;

  #pragma unroll
  for (int k = 0; k < 6; ++k){
    #pragma unroll
    for (int m = 0; m < 3; ++m){
      bf16x8 A = *(const bf16x8*)((const char*)wp3 + ((size_t)((k*3 + m)*64 + l))*16);
      acc[m] = __builtin_amdgcn_mfma_f32_32x32x16_bf16(A, B[k], acc[m], 0, 0, 0);
    }
  }
  #pragma unroll
  for (int m = 0; m < 3; ++m){
    #pragma unroll
    for (int r = 0; r < 16; ++r){
      int o = m*32 + (r & 3) + 8*(r >> 2) + 4*hi;
      outp[((size_t)(b*CCH + o))*HW + pp] = acc[m][r] + b_proj[o];
    }
  }
}

// ---------------------------------------------------------------------------
extern "C" void kernel_launch(void* const* d_in, const int* in_sizes, int n_in,
                              void* d_out, int out_size, void* d_ws, size_t ws_size,
                              hipStream_t stream){
  fp32p x          = (fp32p)d_in[0];
  fp32p w_qkv      = (fp32p)d_in[1];
  fp32p b_qkv      = (fp32p)d_in[2];
  fp32p w_dm       = (fp32p)d_in[3];
  fp32p b_dm       = (fp32p)d_in[4];
  fp32p bias_table = (fp32p)d_in[5];
  fp32p w_proj     = (fp32p)d_in[6];
  fp32p b_proj     = (fp32p)d_in[7];

  char* ws = (char*)d_ws;
  const size_t XBF_BYTES   = (size_t)BATCH * HW * 96 * 2;  // 4,816,896
  const size_t PLANE_BYTES = (size_t)NIMG * HW * 32 * 2;   // 4,816,896
  const size_t TMP2_BYTES  = (size_t)BATCH * HW * 96 * 2;  // 4,816,896
  const size_t W3_BYTES    = 200704ull * 2;
  size_t off = 0;
  ushort_t* xbf    = (ushort_t*)(ws + off); off += XBF_BYTES;
  ushort_t* qplane = (ushort_t*)(ws + off); off += PLANE_BYTES;
  ushort_t* kplane = (ushort_t*)(ws + off); off += PLANE_BYTES;
  ushort_t* v2     = (ushort_t*)(ws + off); off += PLANE_BYTES;
  ushort_t* tmp2   = (ushort_t*)(ws + off); off += TMP2_BYTES;
  __hip_bfloat16* w3 = (__hip_bfloat16*)(ws + off); off += W3_BYTES;
  float* bias3     = (float*)(ws + off);    off += 192*4;
  ushort_t* wq3    = (ushort_t*)(ws + off); off += 27648*2;
  ushort_t* wp3    = (ushort_t*)(ws + off); off += 9216*2;

  hipLaunchKernelGGL(prep_xt_kernel, dim3(1125), dim3(256), 0, stream,
                     w_dm, b_dm, bias_table, w_qkv, w_proj, x,
                     w3, bias3, wq3, wp3, xbf);
  hipLaunchKernelGGL(qkv_kernel, dim3(784), dim3(192), 0, stream,
                     xbf, wq3, b_qkv, qplane, kplane, v2);
  hipLaunchKernelGGL(attn_kernel, dim3(672), dim3(256), 0, stream,
                     qplane, kplane, w3, bias3, v2, tmp2);
  hipLaunchKernelGGL(proj_kernel, dim3(784), dim3(64), 0, stream,
                     tmp2, wp3, b_proj, (float*)d_out);
}

// Round 10
// 74.611 us; speedup vs baseline: 1.0069x; 1.0069x over previous
//
#include <hip/hip_runtime.h>
#include <hip/hip_bf16.h>
#include <stdint.h>

#define BATCH 8
#define CCH 96
#define NH 3
#define HD 32
#define HGT 56
#define WID 56
#define HW 3136
#define WIN 7
#define KK 49
#define PADR 3
#define NIMG 24   // BATCH*NH
#define C2 64     // 2*HD

typedef const float* fp32p;
typedef __attribute__((ext_vector_type(8))) short bf16x8;
typedef __attribute__((ext_vector_type(16))) float f32x16;
typedef __attribute__((ext_vector_type(2))) float f32x2;
typedef unsigned short ushort_t;

__device__ __forceinline__ float bf2f_bits(unsigned u){ return __uint_as_float(u << 16); }
__device__ __forceinline__ ushort_t f2bf_bits(float f){
  __hip_bfloat16 hb = __float2bfloat16(f);
  return *(ushort_t*)&hb;
}

// ---------------------------------------------------------------------------
// prep+xt fused: blocks [0,929) weight prep, [929,1125) transpose x.
// ---------------------------------------------------------------------------
__global__ __launch_bounds__(256) void prep_xt_kernel(fp32p w_dm, fp32p b_dm,
    fp32p bias_table, fp32p w_qkv, fp32p w_proj, fp32p x,
    __hip_bfloat16* __restrict__ w3, float* __restrict__ bias3,
    ushort_t* __restrict__ wq3, ushort_t* __restrict__ wp3,
    ushort_t* __restrict__ xbf){
  __shared__ float lds[128*97];
  int bx = blockIdx.x;
  if (bx < 929){
    int t = bx * 256 + threadIdx.x;
    if (t < 200704){
      int j   = t & 7;
      int l   = (t >> 3) & 63;
      int mt  = (t >> 9) & 1;
      int cb  = (t >> 10) & 1;
      int pt  = t >> 11;            // pass*49 + tap
      int pass = pt / KK, tap = pt % KK;
      int o  = mt*32 + (l & 31);
      int ch = pass*32 + cb*16 + (l >> 5)*8 + j;
      float v = 0.f;
      if (o < KK) v = w_dm[((size_t)(o*C2 + ch))*KK + tap];
      w3[t] = __float2bfloat16(v);
    } else if (t < 200896){
      int t2 = t - 200704;
      int h = t2 >> 6;
      int o = t2 & 63;
      bias3[t2] = (o < KK) ? (b_dm[o] + bias_table[o*NH + h]) : -1e30f;
    } else if (t < 200896 + 27648){
      int i = t - 200896;
      int j = i & 7, l = (i >> 3) & 63;
      int rest = i >> 9;            // k*9 + mt
      int mt = rest % 9, k = rest / 9;
      int o = mt*32 + (l & 31);
      int c = k*16 + (l >> 5)*8 + j;
      wq3[i] = f2bf_bits(w_qkv[o*CCH + c]);
    } else if (t < 200896 + 27648 + 9216){
      int i = t - 200896 - 27648;
      int j = i & 7, l = (i >> 3) & 63;
      int rest = i >> 9;            // k*3 + mt
      int mt = rest % 3, k = rest / 3;
      int o = mt*32 + (l & 31);
      int c = k*16 + (l >> 5)*8 + j;
      wp3[i] = f2bf_bits(w_proj[o*CCH + c]);
    }
  } else {
    int px0 = (bx - 929) * 128;
    int tid = threadIdx.x;
    #pragma unroll
    for (int it = 0; it < 48; ++it){
      int s = tid + it*256;         // 12288 = 128 px * 96 c, px fastest
      int px = s & 127;
      int c  = s >> 7;
      int gpx = px0 + px;
      int b = gpx / HW, pp = gpx % HW;
      lds[px*97 + c] = x[((size_t)b*CCH + c)*HW + pp];
    }
    __syncthreads();
    #pragma unroll
    for (int it = 0; it < 6; ++it){
      int s = tid + it*256;         // 1536 = 128 px * 12 chunks
      int j  = s % 12;
      int px = s / 12;
      unsigned u[4];
      #pragma unroll
      for (int q = 0; q < 4; ++q){
        float f0 = lds[px*97 + j*8 + 2*q];
        float f1 = lds[px*97 + j*8 + 2*q + 1];
        u[q] = (unsigned)f2bf_bits(f0) | ((unsigned)f2bf_bits(f1) << 16);
      }
      uint4 w4; w4.x=u[0]; w4.y=u[1]; w4.z=u[2]; w4.w=u[3];
      *(uint4*)((char*)xbf + ((size_t)(px0+px)*96 + j*8)*2) = w4;
    }
  }
}

// ---------------------------------------------------------------------------
// qkv GEMM: wave = M96 (3 mt = 3 heads) x N32.
// grid = 3 m-groups (sec) x 784 px-tiles, 64-thread WGs. (R8 proven form;
// R9's 3-wave merge regressed ~0.5us.)
// ---------------------------------------------------------------------------
__global__ __launch_bounds__(64) void qkv_kernel(const ushort_t* __restrict__ xbf,
    const ushort_t* __restrict__ wq3, fp32p b_qkv,
    ushort_t* __restrict__ qplane, ushort_t* __restrict__ kplane,
    ushort_t* __restrict__ v2){
  int wid = blockIdx.x;
  int g  = wid / 784;             // sec: 0=q,1=k,2=v
  int pt = wid % 784;
  int l = threadIdx.x & 63, col = l & 31, hi = l >> 5;
  int px = pt*32 + col;
  int b = px / HW, pp = px % HW;

  bf16x8 B[6];
  const char* bb = (const char*)xbf + (size_t)px*192 + hi*16;
  #pragma unroll
  for (int k = 0; k < 6; ++k) B[k] = *(const bf16x8*)(bb + k*32);

  f32x16 acc[3];
  #pragma unroll
  for (int m = 0; m < 3; ++m)
    #pragma unroll
    for (int r = 0; r < 16; ++r) acc[m][r] = 0.f;

  #pragma unroll
  for (int k = 0; k < 6; ++k){
    #pragma unroll
    for (int m = 0; m < 3; ++m){
      bf16x8 A = *(const bf16x8*)((const char*)wq3 + ((size_t)((k*9 + g*3 + m)*64 + l))*16);
      acc[m] = __builtin_amdgcn_mfma_f32_32x32x16_bf16(A, B[k], acc[m], 0, 0, 0);
    }
  }
  const float scale = 0.17677669529663687f;
  ushort_t* plane = (g == 0) ? qplane : (g == 1 ? kplane : v2);
  #pragma unroll
  for (int m = 0; m < 3; ++m){    // head = m, ch = rowv
    ushort_t* dst = plane + ((size_t)((b*NH + m)*HW + pp))*32;
    #pragma unroll
    for (int q = 0; q < 4; ++q){
      int base = 8*q + 4*hi;      // rowv base; r = q*4+e -> rowv = base+e
      float v0 = acc[m][q*4+0] + b_qkv[g*96 + m*32 + base + 0];
      float v1 = acc[m][q*4+1] + b_qkv[g*96 + m*32 + base + 1];
      float v2f = acc[m][q*4+2] + b_qkv[g*96 + m*32 + base + 2];
      float v3 = acc[m][q*4+3] + b_qkv[g*96 + m*32 + base + 3];
      if (g == 0){ v0 *= scale; v1 *= scale; v2f *= scale; v3 *= scale; }
      uint2 pk;
      pk.x = (unsigned)f2bf_bits(v0) | ((unsigned)f2bf_bits(v1) << 16);
      pk.y = (unsigned)f2bf_bits(v2f) | ((unsigned)f2bf_bits(v3) << 16);
      *(uint2*)(&dst[base]) = pk;
    }
  }
}

// ---------------------------------------------------------------------------
// attn fused. R10 = R8 core (proven 47.9us) + K-halo reg-preload: pass-1's
// 8 global loads are issued BEFORE pass-0's conv loop and pinned by an asm
// anchor after it, so their latency hides under ~3000cyc of conv instead of
// sitting exposed between two barriers. V-preload likewise anchored.
// Conv: depth-2 pipeline, K-split waves (row, cbw), M64 x N64 x K16.
// XCD-clustered blocks (FETCH 28.9->8.8MB, R8).
// LDS: [0,32KB) qk halo / exchange / V; [32KB,49KB) P (stride 68).
// ---------------------------------------------------------------------------
#define MFMA4K(Ab, Bb) \
  { _Pragma("unroll") for (int nt = 0; nt < 2; ++nt){ \
      acc[0][nt] = __builtin_amdgcn_mfma_f32_32x32x16_bf16(Ab[0], Bb[nt], acc[0][nt], 0, 0, 0); \
      acc[1][nt] = __builtin_amdgcn_mfma_f32_32x32x16_bf16(Ab[1], Bb[nt], acc[1][nt], 0, 0, 0); \
    } }

#define LOADAK(tt, Ab) \
  { const char* An_ = Abase + (size_t)(tt)*4096; \
    Ab[0] = *(const bf16x8*)(An_); \
    Ab[1] = *(const bf16x8*)(An_ + 1024); }

#define LOADBK(tt, Bb) \
  { int ky_ = (tt) / 7, kx_ = (tt) - ky_*7; \
    _Pragma("unroll") for (int nt = 0; nt < 2; ++nt){ \
      int xp_ = nt*32 + col + kx_; if (xp_ > 61) xp_ = 61; \
      int base_ = ((row + ky_)*64 + xp_)*64; \
      int sx_ = (xp_ & 3) ^ ((xp_ >> 2) & 3); \
      Bb[nt] = *(const bf16x8*)(&smem[base_ + ((((cbw << 1) | hi) ^ sx_) << 4)]); } }

#define CONVPASS(PASSIDX) \
  { const char* Abase = (const char*)w3 + (size_t)(PASSIDX)*KK*4096 + cbw*2048 + l*16; \
    bf16x8 A0[2], A1[2], B0[2], B1[2]; \
    LOADAK(0, A0); LOADBK(0, B0); \
    LOADAK(1, A1); LOADBK(1, B1); \
    for (int t = 0; t < 48; t += 2){ \
      MFMA4K(A0, B0); \
      LOADAK(t+2, A0); LOADBK(t+2, B0); \
      MFMA4K(A1, B1); \
      int t3 = (t+3 < KK) ? (t+3) : 48; \
      LOADAK(t3, A1); LOADBK(t3, B1); \
    } \
    MFMA4K(A0, B0); }

// exchange: chunk index within a px row = mt*8 + 2q + hi, XOR col&15 for banks
#define XWRITE(A0v, A1v) \
  { _Pragma("unroll") for (int q = 0; q < 4; ++q){ \
      float4 v4; \
      v4.x=A0v[4*q+0]; v4.y=A0v[4*q+1]; v4.z=A0v[4*q+2]; v4.w=A0v[4*q+3]; \
      *(float4*)((char*)xch + slot_o*256 + (((2*q+hi) ^ xsw)<<4)) = v4; \
      v4.x=A1v[4*q+0]; v4.y=A1v[4*q+1]; v4.z=A1v[4*q+2]; v4.w=A1v[4*q+3]; \
      *(float4*)((char*)xch + slot_o*256 + (((8+2*q+hi) ^ xsw)<<4)) = v4; } }

#define XREAD(A0v, A1v) \
  { _Pragma("unroll") for (int q = 0; q < 4; ++q){ \
      float4 v4 = *(const float4*)((char*)xch + slot_s*256 + (((2*q+hi) ^ xsw)<<4)); \
      A0v[4*q+0]+=v4.x; A0v[4*q+1]+=v4.y; A0v[4*q+2]+=v4.z; A0v[4*q+3]+=v4.w; \
      v4 = *(const float4*)((char*)xch + slot_s*256 + (((8+2*q+hi) ^ xsw)<<4)); \
      A1v[4*q+0]+=v4.x; A1v[4*q+1]+=v4.y; A1v[4*q+2]+=v4.z; A1v[4*q+3]+=v4.w; } }

__global__ __launch_bounds__(256, 3) void attn_kernel(
    const ushort_t* __restrict__ qplane, const ushort_t* __restrict__ kplane,
    const __hip_bfloat16* __restrict__ w3, const float* __restrict__ bias3,
    const ushort_t* __restrict__ v2, ushort_t* __restrict__ tmp2){
  __shared__ char smem[50176];

  int d = blockIdx.x;
  int bid = (d & 7)*84 + (d >> 3);  // XCD-cluster: 84 consecutive blocks/XCD
  int n  = bid / 28;
  int y0 = (bid % 28) * 2;
  int b = n / NH, head = n % NH;
  int tid = threadIdx.x;
  int l = tid & 63, w = tid >> 6, hi = l >> 5, col = l & 31;
  int row = w >> 1;               // output row within the pair
  int cbw = w & 1;                // K-half this wave accumulates

  f32x16 acc[2][2];               // [mt][nt] partial sums for K-half cbw
  #pragma unroll
  for (int r = 0; r < 16; ++r){
    int rowv = (r & 3) + 8*(r >> 2) + 4*hi;
    float b0 = (cbw == 0) ? bias3[head*64 + rowv] : 0.f;
    float b1 = (cbw == 0) ? bias3[head*64 + 32 + rowv] : 0.f;
    #pragma unroll
    for (int nt = 0; nt < 2; ++nt){ acc[0][nt][r] = b0; acc[1][nt][r] = b1; }
  }

  // staging-chunk decomposition (shared by Q stage, K preload, K write)
  int sc_c  = tid & 3;            // it-th chunk: s = tid + it*256
  // Q halo stage (fused global->reg->LDS)
  {
    const char* src = (const char*)qplane + (size_t)n * HW * 64;
    #pragma unroll
    for (int it = 0; it < 8; ++it){
      int s = tid + it*256;       // 2048 16B chunks: 8 rows x 64 xp x 4 c
      int c   = s & 3;
      int xp  = (s >> 2) & 63;
      int rw  = s >> 8;
      int gy = y0 - 3 + rw;
      int gx = xp - 3;
      uint4 val = {0,0,0,0};
      if ((unsigned)gy < HGT && (unsigned)gx < WID)
        val = *(const uint4*)(src + (size_t)(gy*WID + gx)*64 + c*16);
      int sw = (c ^ (xp & 3) ^ ((xp >> 2) & 3)) << 4;
      *(uint4*)(&smem[(rw*64 + xp)*64 + sw]) = val;
    }
  }
  // K halo preload to regs: issued HERE so its latency hides under conv pass0
  uint4 kreg[8];
  {
    const char* src = (const char*)kplane + (size_t)n * HW * 64;
    #pragma unroll
    for (int it = 0; it < 8; ++it){
      int s = tid + it*256;
      int c   = s & 3;
      int xp  = (s >> 2) & 63;
      int rw  = s >> 8;
      int gy = y0 - 3 + rw;
      int gx = xp - 3;
      uint4 val = {0,0,0,0};
      if ((unsigned)gy < HGT && (unsigned)gx < WID)
        val = *(const uint4*)(src + (size_t)(gy*WID + gx)*64 + c*16);
      kreg[it] = val;
    }
  }
  __syncthreads();

  CONVPASS(0);

  // pin: K loads must be resident by now (issued before conv, waited here)
  asm volatile("" :: "v"(kreg[0].x), "v"(kreg[1].x), "v"(kreg[2].x),
                     "v"(kreg[3].x), "v"(kreg[4].x), "v"(kreg[5].x),
                     "v"(kreg[6].x), "v"(kreg[7].x));
  __syncthreads();                // all waves done reading Q halo
  #pragma unroll
  for (int it = 0; it < 8; ++it){ // K halo: pure ds_writes from regs
    int s = tid + it*256;
    int c   = s & 3;
    int xp  = (s >> 2) & 63;
    int rw  = s >> 8;
    int sw = (c ^ (xp & 3) ^ ((xp >> 2) & 3)) << 4;
    *(uint4*)(&smem[(rw*64 + xp)*64 + sw]) = kreg[it];
  }
  __syncthreads();

  CONVPASS(1);
  (void)sc_c;

  // cross-wave cb-partial exchange via dead qk-halo LDS. Wave (row,cbw)
  // writes px-half (1-cbw), reads+merges its own half cbw.
  __syncthreads();                // all waves done reading qk halo
  float* xch = (float*)smem;
  int xsw = col & 15;
  {
    int slot_o = row*64 + (1-cbw)*32 + col;
    if (cbw == 0){ XWRITE(acc[0][1], acc[1][1]); }
    else         { XWRITE(acc[0][0], acc[1][0]); }
  }
  __syncthreads();
  f32x16 a0, a1;                  // merged logits for owned px-half
  {
    int slot_s = row*64 + cbw*32 + col;
    if (cbw == 0){ XREAD(acc[0][0], acc[1][0]); a0 = acc[0][0]; a1 = acc[1][0]; }
    else         { XREAD(acc[0][1], acc[1][1]); a0 = acc[0][1]; a1 = acc[1][1]; }
  }

  // V preload (global->reg); anchored after P-stores so issue happens here
  const char* vb = (const char*)v2 + (size_t)n * HW * 64;
  uint4 vreg[8];
  #pragma unroll
  for (int it = 0; it < 8; ++it){
    int s = tid + it*256;         // 2048
    int xp  = s & 63;
    int c   = (s >> 6) & 3;
    int rw  = s >> 8;
    int gy = y0 - 3 + rw;
    int gx = xp - 3;
    uint4 val = {0,0,0,0};
    if ((unsigned)gy < HGT && (unsigned)gx < WID)
      val = *(const uint4*)(vb + (size_t)(gy*WID + gx)*64 + c*16);
    vreg[it] = val;
  }

  // softmax over 64 padded o; P -> LDS [128 px][stride 68] bf16 (b64 stores)
  ushort_t* Pp = (ushort_t*)&smem[32768];
  {
    float m = -1e30f;
    #pragma unroll
    for (int r = 0; r < 16; ++r){ m = fmaxf(m, a0[r]); m = fmaxf(m, a1[r]); }
    m = fmaxf(m, __shfl_xor(m, 32));
    float s = 0.f;
    #pragma unroll
    for (int r = 0; r < 16; ++r){
      a0[r] = __expf(a0[r] - m); s += a0[r];
      a1[r] = __expf(a1[r] - m); s += a1[r];
    }
    s += __shfl_xor(s, 32);
    float inv = 1.f / s;
    int pixslot = row*64 + cbw*32 + col;
    ushort_t* Pr = Pp + pixslot*68;
    #pragma unroll
    for (int q = 0; q < 4; ++q){
      int base = 8*q + 4*hi;      // rowv base; r = q*4+e -> rowv = base+e
      uint2 pk0;
      pk0.x = (unsigned)f2bf_bits(a0[q*4+0]*inv) | ((unsigned)f2bf_bits(a0[q*4+1]*inv) << 16);
      pk0.y = (unsigned)f2bf_bits(a0[q*4+2]*inv) | ((unsigned)f2bf_bits(a0[q*4+3]*inv) << 16);
      *(uint2*)(&Pr[base]) = pk0;
      uint2 pk1;                  // o = 32+base..+3; slots >=49 never read by PV
      pk1.x = (unsigned)f2bf_bits(a1[q*4+0]*inv) | ((unsigned)f2bf_bits(a1[q*4+1]*inv) << 16);
      pk1.y = (unsigned)f2bf_bits(a1[q*4+2]*inv) | ((unsigned)f2bf_bits(a1[q*4+3]*inv) << 16);
      *(uint2*)(&Pr[32 + base]) = pk1;
    }
  }
  // anchor: V loads issued before this point, latency hidden under softmax
  asm volatile("" :: "v"(vreg[0].x), "v"(vreg[1].x), "v"(vreg[2].x),
                     "v"(vreg[3].x), "v"(vreg[4].x), "v"(vreg[5].x),
                     "v"(vreg[6].x), "v"(vreg[7].x));
  __syncthreads();                // exchange reads + P writes all done

  // V restage from regs, transposed: [c4][row8][xp64][16B] -> conflict-free PV
  #pragma unroll
  for (int it = 0; it < 8; ++it){
    int s = tid + it*256;         // 2048
    int xp  = s & 63;
    int c   = (s >> 6) & 3;
    int rw  = s >> 8;
    *(uint4*)(&smem[((c*8 + rw)*64 + xp)*16]) = vreg[it];
  }
  __syncthreads();

  // PV: 2 threads per px (128 slots x 2 ch-halves), 16 ch each.
  int ch2 = tid >> 7;             // channel half
  int slot = tid & 127;
  int pr = slot >> 6, pxx = slot & 63;
  if (pxx < WID){
    f32x2 out2[8];                // [ci*4+q] = channel pair (2q, 2q+1) of ci
    #pragma unroll
    for (int i = 0; i < 8; ++i){ out2[i].x = 0.f; out2[i].y = 0.f; }
    #pragma unroll
    for (int ky = 0; ky < WIN; ++ky){
      #pragma unroll
      for (int kx = 0; kx < WIN; ++kx){
        float pw = bf2f_bits(Pp[slot*68 + ky*7 + kx]);
        f32x2 pw2; pw2.x = pw; pw2.y = pw;
        int vrow = pr + ky, xp = pxx + kx;
        #pragma unroll
        for (int ci = 0; ci < 2; ++ci){
          int cc = ch2*2 + ci;
          uint4 vv = *(const uint4*)(&smem[((cc*8 + vrow)*64 + xp)*16]);
          unsigned ua[4] = {vv.x, vv.y, vv.z, vv.w};
          #pragma unroll
          for (int q = 0; q < 4; ++q){
            f32x2 v2f;
            v2f.x = __uint_as_float(ua[q] << 16);
            v2f.y = __uint_as_float(ua[q] & 0xffff0000u);
            out2[ci*4 + q] += pw2 * v2f;
          }
        }
      }
    }
    int pp = (y0 + pr)*WID + pxx;
    ushort_t* dst = tmp2 + ((size_t)(b*HW + pp))*96 + head*32 + ch2*16;
    #pragma unroll
    for (int j2 = 0; j2 < 2; ++j2){
      unsigned u[4];
      #pragma unroll
      for (int q = 0; q < 4; ++q){
        u[q] = (unsigned)f2bf_bits(out2[j2*4 + q].x) | ((unsigned)f2bf_bits(out2[j2*4 + q].y) << 16);
      }
      uint4 w4; w4.x=u[0]; w4.y=u[1]; w4.z=u[2]; w4.w=u[3];
      *(uint4*)(&dst[j2*8]) = w4;
    }
  }
}

// ---------------------------------------------------------------------------
// proj GEMM: wave = M96 x N32; grid = 784 px-tiles (proven form).
// ---------------------------------------------------------------------------
__global__ __launch_bounds__(64) void proj_kernel(const ushort_t* __restrict__ tmp2,
    const ushort_t* __restrict__ wp3, fp32p b_proj, float* __restrict__ outp){
  int pt = blockIdx.x;
  int l = threadIdx.x & 63, col = l & 31, hi = l >> 5;
  int px = pt*32 + col;
  int b = px / HW, pp = px % HW;

  bf16x8 B[6];
  const char* bb = (const char*)tmp2 + (size_t)px*192 + hi*16;
  #pragma unroll
  for (int k = 0; k < 6; ++k) B[k] = *(const bf16x8*)(bb + k*32);

  f32x16 acc[3];
  #pragma unroll
  for (int m = 0; m < 3; ++m)
    #pragma unroll
    for (int r = 0; r < 16; ++r) acc[m][r] = 0.f;

  #pragma unroll
  for (int k = 0; k < 6; ++k){
    #pragma unroll
    for (int m = 0; m < 3; ++m){
      bf16x8 A = *(const bf16x8*)((const char*)wp3 + ((size_t)((k*3 + m)*64 + l))*16);
      acc[m] = __builtin_amdgcn_mfma_f32_32x32x16_bf16(A, B[k], acc[m], 0, 0, 0);
    }
  }
  #pragma unroll
  for (int m = 0; m < 3; ++m){
    #pragma unroll
    for (int r = 0; r < 16; ++r){
      int o = m*32 + (r & 3) + 8*(r >> 2) + 4*hi;
      outp[((size_t)(b*CCH + o))*HW + pp] = acc[m][r] + b_proj[o];
    }
  }
}

// ---------------------------------------------------------------------------
extern "C" void kernel_launch(void* const* d_in, const int* in_sizes, int n_in,
                              void* d_out, int out_size, void* d_ws, size_t ws_size,
                              hipStream_t stream){
  fp32p x          = (fp32p)d_in[0];
  fp32p w_qkv      = (fp32p)d_in[1];
  fp32p b_qkv      = (fp32p)d_in[2];
  fp32p w_dm       = (fp32p)d_in[3];
  fp32p b_dm       = (fp32p)d_in[4];
  fp32p bias_table = (fp32p)d_in[5];
  fp32p w_proj     = (fp32p)d_in[6];
  fp32p b_proj     = (fp32p)d_in[7];

  char* ws = (char*)d_ws;
  const size_t XBF_BYTES   = (size_t)BATCH * HW * 96 * 2;  // 4,816,896
  const size_t PLANE_BYTES = (size_t)NIMG * HW * 32 * 2;   // 4,816,896
  const size_t TMP2_BYTES  = (size_t)BATCH * HW * 96 * 2;  // 4,816,896
  const size_t W3_BYTES    = 200704ull * 2;
  size_t off = 0;
  ushort_t* xbf    = (ushort_t*)(ws + off); off += XBF_BYTES;
  ushort_t* qplane = (ushort_t*)(ws + off); off += PLANE_BYTES;
  ushort_t* kplane = (ushort_t*)(ws + off); off += PLANE_BYTES;
  ushort_t* v2     = (ushort_t*)(ws + off); off += PLANE_BYTES;
  ushort_t* tmp2   = (ushort_t*)(ws + off); off += TMP2_BYTES;
  __hip_bfloat16* w3 = (__hip_bfloat16*)(ws + off); off += W3_BYTES;
  float* bias3     = (float*)(ws + off);    off += 192*4;
  ushort_t* wq3    = (ushort_t*)(ws + off); off += 27648*2;
  ushort_t* wp3    = (ushort_t*)(ws + off); off += 9216*2;

  hipLaunchKernelGGL(prep_xt_kernel, dim3(1125), dim3(256), 0, stream,
                     w_dm, b_dm, bias_table, w_qkv, w_proj, x,
                     w3, bias3, wq3, wp3, xbf);
  hipLaunchKernelGGL(qkv_kernel, dim3(2352), dim3(64), 0, stream,
                     xbf, wq3, b_qkv, qplane, kplane, v2);
  hipLaunchKernelGGL(attn_kernel, dim3(672), dim3(256), 0, stream,
                     qplane, kplane, w3, bias3, v2, tmp2);
  hipLaunchKernelGGL(proj_kernel, dim3(784), dim3(64), 0, stream,
                     tmp2, wp3, b_proj, (float*)d_out);
}

// Round 11
// 71.247 us; speedup vs baseline: 1.0544x; 1.0472x over previous
//
#include <hip/hip_runtime.h>
#include <hip/hip_bf16.h>
#include <stdint.h>

#define BATCH 8
#define CCH 96
#define NH 3
#define HD 32
#define HGT 56
#define WID 56
#define HW 3136
#define WIN 7
#define KK 49
#define PADR 3
#define NIMG 24   // BATCH*NH
#define C2 64     // 2*HD

typedef const float* fp32p;
typedef __attribute__((ext_vector_type(8))) short bf16x8;
typedef __attribute__((ext_vector_type(16))) float f32x16;
typedef __attribute__((ext_vector_type(2))) float f32x2;
typedef unsigned short ushort_t;

__device__ __forceinline__ float bf2f_bits(unsigned u){ return __uint_as_float(u << 16); }
__device__ __forceinline__ ushort_t f2bf_bits(float f){
  __hip_bfloat16 hb = __float2bfloat16(f);
  return *(ushort_t*)&hb;
}

// ---------------------------------------------------------------------------
// prep: weight prep only (xt is gone — qkv transposes x in-kernel now).
//  w3[pass2][tap49][cb2][mt2][lane64][j8] bf16 (conv A-frags; proven layout)
//  bias3[head3][64] f32
//  wq3[k6][mt9][lane64][j8] bf16, wp3[k6][mt3][lane64][j8] bf16
// ---------------------------------------------------------------------------
__global__ __launch_bounds__(256) void prep_kernel(fp32p w_dm, fp32p b_dm,
    fp32p bias_table, fp32p w_qkv, fp32p w_proj,
    __hip_bfloat16* __restrict__ w3, float* __restrict__ bias3,
    ushort_t* __restrict__ wq3, ushort_t* __restrict__ wp3){
  int t = blockIdx.x * 256 + threadIdx.x;
  if (t < 200704){
    int j   = t & 7;
    int l   = (t >> 3) & 63;
    int mt  = (t >> 9) & 1;
    int cb  = (t >> 10) & 1;
    int pt  = t >> 11;            // pass*49 + tap
    int pass = pt / KK, tap = pt % KK;
    int o  = mt*32 + (l & 31);
    int ch = pass*32 + cb*16 + (l >> 5)*8 + j;
    float v = 0.f;
    if (o < KK) v = w_dm[((size_t)(o*C2 + ch))*KK + tap];
    w3[t] = __float2bfloat16(v);
  } else if (t < 200896){
    int t2 = t - 200704;
    int h = t2 >> 6;
    int o = t2 & 63;
    bias3[t2] = (o < KK) ? (b_dm[o] + bias_table[o*NH + h]) : -1e30f;
  } else if (t < 200896 + 27648){
    int i = t - 200896;
    int j = i & 7, l = (i >> 3) & 63;
    int rest = i >> 9;            // k*9 + mt
    int mt = rest % 9, k = rest / 9;
    int o = mt*32 + (l & 31);
    int c = k*16 + (l >> 5)*8 + j;
    wq3[i] = f2bf_bits(w_qkv[o*CCH + c]);
  } else if (t < 200896 + 27648 + 9216){
    int i = t - 200896 - 27648;
    int j = i & 7, l = (i >> 3) & 63;
    int rest = i >> 9;            // k*3 + mt
    int mt = rest % 3, k = rest / 3;
    int o = mt*32 + (l & 31);
    int c = k*16 + (l >> 5)*8 + j;
    wp3[i] = f2bf_bits(w_proj[o*CCH + c]);
  }
}

// ---------------------------------------------------------------------------
// qkv GEMM (R11): reads x DIRECTLY (channel-major f32), transposing its
// 32-px tile through LDS — eliminates the xt kernel and the xbf roundtrip
// (~14.4 MB HBM + one launch). Transpose done per (g,pt) block (3x per tile,
// but ~170 VALU in a latency-bound 1-wave kernel). Stride-97 LDS:
// 97 mod 32 = 1 -> conflict-free transposed reads.
// wave = M96 (3 mt = 3 heads) x N32; grid = 3 x 784, 64-thread WGs.
// HW = 3136 = 98*32, so 32-px tiles never straddle an image boundary.
// ---------------------------------------------------------------------------
__global__ __launch_bounds__(64) void qkv_kernel(fp32p x,
    const ushort_t* __restrict__ wq3, fp32p b_qkv,
    ushort_t* __restrict__ qplane, ushort_t* __restrict__ kplane,
    ushort_t* __restrict__ v2){
  __shared__ float lds[32*97];
  int wid = blockIdx.x;
  int g  = wid / 784;             // sec: 0=q,1=k,2=v
  int pt = wid % 784;
  int l = threadIdx.x & 63, col = l & 31, hi = l >> 5;
  int b = pt / 98;
  int pp0 = (pt % 98) * 32;
  int pp = pp0 + col;

  // stage x[b][0..95][pp0..pp0+31] -> lds[px][c] (coalesced 2x128B per it)
  #pragma unroll
  for (int it = 0; it < 48; ++it){
    int s = (int)threadIdx.x + it*64;   // 3072 = 96 c x 32 px
    int c = s >> 5, pxi = s & 31;
    lds[pxi*97 + c] = x[((size_t)b*CCH + c)*HW + pp0 + pxi];
  }
  __syncthreads();

  // B-frags from transposed tile: lane reads 8 consecutive ch of its pixel
  bf16x8 B[6];
  #pragma unroll
  for (int k = 0; k < 6; ++k){
    unsigned u[4];
    #pragma unroll
    for (int q = 0; q < 4; ++q){
      float f0 = lds[col*97 + k*16 + hi*8 + 2*q];
      float f1 = lds[col*97 + k*16 + hi*8 + 2*q + 1];
      u[q] = (unsigned)f2bf_bits(f0) | ((unsigned)f2bf_bits(f1) << 16);
    }
    unsigned* bp = (unsigned*)&B[k];
    bp[0] = u[0]; bp[1] = u[1]; bp[2] = u[2]; bp[3] = u[3];
  }

  f32x16 acc[3];
  #pragma unroll
  for (int m = 0; m < 3; ++m)
    #pragma unroll
    for (int r = 0; r < 16; ++r) acc[m][r] = 0.f;

  #pragma unroll
  for (int k = 0; k < 6; ++k){
    #pragma unroll
    for (int m = 0; m < 3; ++m){
      bf16x8 A = *(const bf16x8*)((const char*)wq3 + ((size_t)((k*9 + g*3 + m)*64 + l))*16);
      acc[m] = __builtin_amdgcn_mfma_f32_32x32x16_bf16(A, B[k], acc[m], 0, 0, 0);
    }
  }
  const float scale = 0.17677669529663687f;
  ushort_t* plane = (g == 0) ? qplane : (g == 1 ? kplane : v2);
  #pragma unroll
  for (int m = 0; m < 3; ++m){    // head = m, ch = rowv
    ushort_t* dst = plane + ((size_t)((b*NH + m)*HW + pp))*32;
    #pragma unroll
    for (int q = 0; q < 4; ++q){
      int base = 8*q + 4*hi;      // rowv base; r = q*4+e -> rowv = base+e
      float v0 = acc[m][q*4+0] + b_qkv[g*96 + m*32 + base + 0];
      float v1 = acc[m][q*4+1] + b_qkv[g*96 + m*32 + base + 1];
      float v2f = acc[m][q*4+2] + b_qkv[g*96 + m*32 + base + 2];
      float v3 = acc[m][q*4+3] + b_qkv[g*96 + m*32 + base + 3];
      if (g == 0){ v0 *= scale; v1 *= scale; v2f *= scale; v3 *= scale; }
      uint2 pk;
      pk.x = (unsigned)f2bf_bits(v0) | ((unsigned)f2bf_bits(v1) << 16);
      pk.y = (unsigned)f2bf_bits(v2f) | ((unsigned)f2bf_bits(v3) << 16);
      *(uint2*)(&dst[base]) = pk;
    }
  }
}

// ---------------------------------------------------------------------------
// attn fused (R8 verbatim — proven 47.9us; R9/R10 scheduling additions were
// neutral and are dropped). XCD-clustered block remap (FETCH 28.9->8.8MB);
// waves split K: wave = (row, cbw), M64 x N64 x K16, depth-2 pipeline;
// cb-partial exchange via dead halo LDS; packed P-store (stride 68);
// PV with f32x2 accumulators.
// LDS: [0,32KB) qk halo / exchange / V; [32KB,49KB) P.
// ---------------------------------------------------------------------------
#define MFMA4K(Ab, Bb) \
  { _Pragma("unroll") for (int nt = 0; nt < 2; ++nt){ \
      acc[0][nt] = __builtin_amdgcn_mfma_f32_32x32x16_bf16(Ab[0], Bb[nt], acc[0][nt], 0, 0, 0); \
      acc[1][nt] = __builtin_amdgcn_mfma_f32_32x32x16_bf16(Ab[1], Bb[nt], acc[1][nt], 0, 0, 0); \
    } }

#define LOADAK(tt, Ab) \
  { const char* An_ = Abase + (size_t)(tt)*4096; \
    Ab[0] = *(const bf16x8*)(An_); \
    Ab[1] = *(const bf16x8*)(An_ + 1024); }

#define LOADBK(tt, Bb) \
  { int ky_ = (tt) / 7, kx_ = (tt) - ky_*7; \
    _Pragma("unroll") for (int nt = 0; nt < 2; ++nt){ \
      int xp_ = nt*32 + col + kx_; if (xp_ > 61) xp_ = 61; \
      int base_ = ((row + ky_)*64 + xp_)*64; \
      int sx_ = (xp_ & 3) ^ ((xp_ >> 2) & 3); \
      Bb[nt] = *(const bf16x8*)(&smem[base_ + ((((cbw << 1) | hi) ^ sx_) << 4)]); } }

// exchange: chunk index within a px row = mt*8 + 2q + hi, XOR col&15 for banks
#define XWRITE(A0v, A1v) \
  { _Pragma("unroll") for (int q = 0; q < 4; ++q){ \
      float4 v4; \
      v4.x=A0v[4*q+0]; v4.y=A0v[4*q+1]; v4.z=A0v[4*q+2]; v4.w=A0v[4*q+3]; \
      *(float4*)((char*)xch + slot_o*256 + (((2*q+hi) ^ xsw)<<4)) = v4; \
      v4.x=A1v[4*q+0]; v4.y=A1v[4*q+1]; v4.z=A1v[4*q+2]; v4.w=A1v[4*q+3]; \
      *(float4*)((char*)xch + slot_o*256 + (((8+2*q+hi) ^ xsw)<<4)) = v4; } }

#define XREAD(A0v, A1v) \
  { _Pragma("unroll") for (int q = 0; q < 4; ++q){ \
      float4 v4 = *(const float4*)((char*)xch + slot_s*256 + (((2*q+hi) ^ xsw)<<4)); \
      A0v[4*q+0]+=v4.x; A0v[4*q+1]+=v4.y; A0v[4*q+2]+=v4.z; A0v[4*q+3]+=v4.w; \
      v4 = *(const float4*)((char*)xch + slot_s*256 + (((8+2*q+hi) ^ xsw)<<4)); \
      A1v[4*q+0]+=v4.x; A1v[4*q+1]+=v4.y; A1v[4*q+2]+=v4.z; A1v[4*q+3]+=v4.w; } }

__global__ __launch_bounds__(256, 3) void attn_kernel(
    const ushort_t* __restrict__ qplane, const ushort_t* __restrict__ kplane,
    const __hip_bfloat16* __restrict__ w3, const float* __restrict__ bias3,
    const ushort_t* __restrict__ v2, ushort_t* __restrict__ tmp2){
  __shared__ char smem[50176];

  int d = blockIdx.x;
  int bid = (d & 7)*84 + (d >> 3);  // XCD-cluster: 84 consecutive blocks/XCD
  int n  = bid / 28;
  int y0 = (bid % 28) * 2;
  int b = n / NH, head = n % NH;
  int tid = threadIdx.x;
  int l = tid & 63, w = tid >> 6, hi = l >> 5, col = l & 31;
  int row = w >> 1;               // output row within the pair
  int cbw = w & 1;                // K-half this wave accumulates

  f32x16 acc[2][2];               // [mt][nt] partial sums for K-half cbw
  #pragma unroll
  for (int r = 0; r < 16; ++r){
    int rowv = (r & 3) + 8*(r >> 2) + 4*hi;
    float b0 = (cbw == 0) ? bias3[head*64 + rowv] : 0.f;
    float b1 = (cbw == 0) ? bias3[head*64 + 32 + rowv] : 0.f;
    #pragma unroll
    for (int nt = 0; nt < 2; ++nt){ acc[0][nt][r] = b0; acc[1][nt][r] = b1; }
  }

  for (int pass = 0; pass < 2; ++pass){
    if (pass) __syncthreads();
    const char* src = (const char*)(pass ? kplane : qplane) + (size_t)n * HW * 64;
    #pragma unroll
    for (int it = 0; it < 8; ++it){
      int s = tid + it*256;       // 2048 16B chunks: 8 rows x 64 xp x 4 c
      int c   = s & 3;
      int xp  = (s >> 2) & 63;
      int rw  = s >> 8;
      int gy = y0 - 3 + rw;
      int gx = xp - 3;
      uint4 val = {0,0,0,0};
      if ((unsigned)gy < HGT && (unsigned)gx < WID)
        val = *(const uint4*)(src + (size_t)(gy*WID + gx)*64 + c*16);
      int sw = (c ^ (xp & 3) ^ ((xp >> 2) & 3)) << 4;
      *(uint4*)(&smem[(rw*64 + xp)*64 + sw]) = val;
    }
    __syncthreads();

    const char* Abase = (const char*)w3 + (size_t)pass*KK*4096 + cbw*2048 + l*16;
    bf16x8 A0[2], A1[2], B0[2], B1[2];
    LOADAK(0, A0); LOADBK(0, B0);
    LOADAK(1, A1); LOADBK(1, B1);
    for (int t = 0; t < 48; t += 2){
      MFMA4K(A0, B0);
      LOADAK(t+2, A0); LOADBK(t+2, B0);
      MFMA4K(A1, B1);
      int t3 = (t+3 < KK) ? (t+3) : 48;
      LOADAK(t3, A1); LOADBK(t3, B1);
    }
    MFMA4K(A0, B0);               // tap 48
  }

  // cross-wave cb-partial exchange via dead qk-halo LDS. Wave (row,cbw)
  // writes px-half (1-cbw), reads+merges its own half cbw.
  __syncthreads();                // all waves done reading qk halo
  float* xch = (float*)smem;
  int xsw = col & 15;
  {
    int slot_o = row*64 + (1-cbw)*32 + col;
    if (cbw == 0){ XWRITE(acc[0][1], acc[1][1]); }
    else         { XWRITE(acc[0][0], acc[1][0]); }
  }
  __syncthreads();
  f32x16 a0, a1;                  // merged logits for owned px-half
  {
    int slot_s = row*64 + cbw*32 + col;
    if (cbw == 0){ XREAD(acc[0][0], acc[1][0]); a0 = acc[0][0]; a1 = acc[1][0]; }
    else         { XREAD(acc[0][1], acc[1][1]); a0 = acc[0][1]; a1 = acc[1][1]; }
  }

  // V preload (global->reg): latency hides under softmax+P+barrier
  const char* vb = (const char*)v2 + (size_t)n * HW * 64;
  uint4 vreg[8];
  #pragma unroll
  for (int it = 0; it < 8; ++it){
    int s = tid + it*256;         // 2048
    int xp  = s & 63;
    int c   = (s >> 6) & 3;
    int rw  = s >> 8;
    int gy = y0 - 3 + rw;
    int gx = xp - 3;
    uint4 val = {0,0,0,0};
    if ((unsigned)gy < HGT && (unsigned)gx < WID)
      val = *(const uint4*)(vb + (size_t)(gy*WID + gx)*64 + c*16);
    vreg[it] = val;
  }

  // softmax over 64 padded o; P -> LDS [128 px][stride 68] bf16 (b64 stores)
  ushort_t* Pp = (ushort_t*)&smem[32768];
  {
    float m = -1e30f;
    #pragma unroll
    for (int r = 0; r < 16; ++r){ m = fmaxf(m, a0[r]); m = fmaxf(m, a1[r]); }
    m = fmaxf(m, __shfl_xor(m, 32));
    float s = 0.f;
    #pragma unroll
    for (int r = 0; r < 16; ++r){
      a0[r] = __expf(a0[r] - m); s += a0[r];
      a1[r] = __expf(a1[r] - m); s += a1[r];
    }
    s += __shfl_xor(s, 32);
    float inv = 1.f / s;
    int pixslot = row*64 + cbw*32 + col;
    ushort_t* Pr = Pp + pixslot*68;
    #pragma unroll
    for (int q = 0; q < 4; ++q){
      int base = 8*q + 4*hi;      // rowv base; r = q*4+e -> rowv = base+e
      uint2 pk0;
      pk0.x = (unsigned)f2bf_bits(a0[q*4+0]*inv) | ((unsigned)f2bf_bits(a0[q*4+1]*inv) << 16);
      pk0.y = (unsigned)f2bf_bits(a0[q*4+2]*inv) | ((unsigned)f2bf_bits(a0[q*4+3]*inv) << 16);
      *(uint2*)(&Pr[base]) = pk0;
      uint2 pk1;                  // o = 32+base..+3; slots >=49 never read by PV
      pk1.x = (unsigned)f2bf_bits(a1[q*4+0]*inv) | ((unsigned)f2bf_bits(a1[q*4+1]*inv) << 16);
      pk1.y = (unsigned)f2bf_bits(a1[q*4+2]*inv) | ((unsigned)f2bf_bits(a1[q*4+3]*inv) << 16);
      *(uint2*)(&Pr[32 + base]) = pk1;
    }
  }
  __syncthreads();                // exchange reads + P writes all done

  // V restage from regs, transposed: [c4][row8][xp64][16B] -> conflict-free PV
  #pragma unroll
  for (int it = 0; it < 8; ++it){
    int s = tid + it*256;         // 2048
    int xp  = s & 63;
    int c   = (s >> 6) & 3;
    int rw  = s >> 8;
    *(uint4*)(&smem[((c*8 + rw)*64 + xp)*16]) = vreg[it];
  }
  __syncthreads();

  // PV: 2 threads per px (128 slots x 2 ch-halves), 16 ch each.
  int ch2 = tid >> 7;             // channel half
  int slot = tid & 127;
  int pr = slot >> 6, pxx = slot & 63;
  if (pxx < WID){
    f32x2 out2[8];                // [ci*4+q] = channel pair (2q, 2q+1) of ci
    #pragma unroll
    for (int i = 0; i < 8; ++i){ out2[i].x = 0.f; out2[i].y = 0.f; }
    #pragma unroll
    for (int ky = 0; ky < WIN; ++ky){
      #pragma unroll
      for (int kx = 0; kx < WIN; ++kx){
        float pw = bf2f_bits(Pp[slot*68 + ky*7 + kx]);
        f32x2 pw2; pw2.x = pw; pw2.y = pw;
        int vrow = pr + ky, xp = pxx + kx;
        #pragma unroll
        for (int ci = 0; ci < 2; ++ci){
          int cc = ch2*2 + ci;
          uint4 vv = *(const uint4*)(&smem[((cc*8 + vrow)*64 + xp)*16]);
          unsigned ua[4] = {vv.x, vv.y, vv.z, vv.w};
          #pragma unroll
          for (int q = 0; q < 4; ++q){
            f32x2 v2f;
            v2f.x = __uint_as_float(ua[q] << 16);
            v2f.y = __uint_as_float(ua[q] & 0xffff0000u);
            out2[ci*4 + q] += pw2 * v2f;
          }
        }
      }
    }
    int pp = (y0 + pr)*WID + pxx;
    ushort_t* dst = tmp2 + ((size_t)(b*HW + pp))*96 + head*32 + ch2*16;
    #pragma unroll
    for (int j2 = 0; j2 < 2; ++j2){
      unsigned u[4];
      #pragma unroll
      for (int q = 0; q < 4; ++q){
        u[q] = (unsigned)f2bf_bits(out2[j2*4 + q].x) | ((unsigned)f2bf_bits(out2[j2*4 + q].y) << 16);
      }
      uint4 w4; w4.x=u[0]; w4.y=u[1]; w4.z=u[2]; w4.w=u[3];
      *(uint4*)(&dst[j2*8]) = w4;
    }
  }
}

// ---------------------------------------------------------------------------
// proj GEMM: wave = M96 x N32; grid = 784 px-tiles (proven form).
// ---------------------------------------------------------------------------
__global__ __launch_bounds__(64) void proj_kernel(const ushort_t* __restrict__ tmp2,
    const ushort_t* __restrict__ wp3, fp32p b_proj, float* __restrict__ outp){
  int pt = blockIdx.x;
  int l = threadIdx.x & 63, col = l & 31, hi = l >> 5;
  int px = pt*32 + col;
  int b = px / HW, pp = px % HW;

  bf16x8 B[6];
  const char* bb = (const char*)tmp2 + (size_t)px*192 + hi*16;
  #pragma unroll
  for (int k = 0; k < 6; ++k) B[k] = *(const bf16x8*)(bb + k*32);

  f32x16 acc[3];
  #pragma unroll
  for (int m = 0; m < 3; ++m)
    #pragma unroll
    for (int r = 0; r < 16; ++r) acc[m][r] = 0.f;

  #pragma unroll
  for (int k = 0; k < 6; ++k){
    #pragma unroll
    for (int m = 0; m < 3; ++m){
      bf16x8 A = *(const bf16x8*)((const char*)wp3 + ((size_t)((k*3 + m)*64 + l))*16);
      acc[m] = __builtin_amdgcn_mfma_f32_32x32x16_bf16(A, B[k], acc[m], 0, 0, 0);
    }
  }
  #pragma unroll
  for (int m = 0; m < 3; ++m){
    #pragma unroll
    for (int r = 0; r < 16; ++r){
      int o = m*32 + (r & 3) + 8*(r >> 2) + 4*hi;
      outp[((size_t)(b*CCH + o))*HW + pp] = acc[m][r] + b_proj[o];
    }
  }
}

// ---------------------------------------------------------------------------
extern "C" void kernel_launch(void* const* d_in, const int* in_sizes, int n_in,
                              void* d_out, int out_size, void* d_ws, size_t ws_size,
                              hipStream_t stream){
  fp32p x          = (fp32p)d_in[0];
  fp32p w_qkv      = (fp32p)d_in[1];
  fp32p b_qkv      = (fp32p)d_in[2];
  fp32p w_dm       = (fp32p)d_in[3];
  fp32p b_dm       = (fp32p)d_in[4];
  fp32p bias_table = (fp32p)d_in[5];
  fp32p w_proj     = (fp32p)d_in[6];
  fp32p b_proj     = (fp32p)d_in[7];

  char* ws = (char*)d_ws;
  const size_t PLANE_BYTES = (size_t)NIMG * HW * 32 * 2;   // 4,816,896
  const size_t TMP2_BYTES  = (size_t)BATCH * HW * 96 * 2;  // 4,816,896
  const size_t W3_BYTES    = 200704ull * 2;
  size_t off = 0;
  ushort_t* qplane = (ushort_t*)(ws + off); off += PLANE_BYTES;
  ushort_t* kplane = (ushort_t*)(ws + off); off += PLANE_BYTES;
  ushort_t* v2     = (ushort_t*)(ws + off); off += PLANE_BYTES;
  ushort_t* tmp2   = (ushort_t*)(ws + off); off += TMP2_BYTES;
  __hip_bfloat16* w3 = (__hip_bfloat16*)(ws + off); off += W3_BYTES;
  float* bias3     = (float*)(ws + off);    off += 192*4;
  ushort_t* wq3    = (ushort_t*)(ws + off); off += 27648*2;
  ushort_t* wp3    = (ushort_t*)(ws + off); off += 9216*2;

  hipLaunchKernelGGL(prep_kernel, dim3(929), dim3(256), 0, stream,
                     w_dm, b_dm, bias_table, w_qkv, w_proj, w3, bias3, wq3, wp3);
  hipLaunchKernelGGL(qkv_kernel, dim3(2352), dim3(64), 0, stream,
                     x, wq3, b_qkv, qplane, kplane, v2);
  hipLaunchKernelGGL(attn_kernel, dim3(672), dim3(256), 0, stream,
                     qplane, kplane, w3, bias3, v2, tmp2);
  hipLaunchKernelGGL(proj_kernel, dim3(784), dim3(64), 0, stream,
                     tmp2, wp3, b_proj, (float*)d_out);
}